// Round 14
// baseline (135.204 us; speedup 1.0000x reference)
//
#include <hip/hip_runtime.h>
#include <math.h>

#define NPTS 131072
#define KCOMP 256
#define DIM 32
#define NREAL 560                 // 528 tight-packed quad + 32 linear
#define NCH 18                    // 32-feature chunks: 17 full + 1 half (16)
#define PSIF_BYTES 294912         // 18 chunks * 1024 granules * 16 B
#define WS_NEED (PSIF_BYTES + KCOMP * 4)

typedef __attribute__((ext_vector_type(8))) short short8;
typedef __attribute__((ext_vector_type(16))) float f32x16;

__device__ __forceinline__ unsigned short f2bf(float v) {
    unsigned u = __float_as_uint(v);
    u += 0x7fffu + ((u >> 16) & 1u);   // RNE
    return (unsigned short)(u >> 16);
}

// pack two f32 -> two bf16 (lo | hi<<16). RTN (+0x8000) + byte-perm: 3 ops.
__device__ __forceinline__ unsigned pkbf(float lo, float hi) {
#if __has_builtin(__builtin_amdgcn_perm)
    const unsigned a = __float_as_uint(hi) + 0x8000u;
    const unsigned b = __float_as_uint(lo) + 0x8000u;
    return __builtin_amdgcn_perm(a, b, 0x07060302u);
#else
    return (unsigned)f2bf(lo) | ((unsigned)f2bf(hi) << 16);
#endif
}

// LDS-only barrier: gen writes are the only shared-memory traffic in the
// main loop; B loads are wave-private register deps and are NOT drained.
__device__ __forceinline__ void barrier_lds() {
    asm volatile("s_waitcnt lgkmcnt(0)\ns_barrier" ::: "memory");
}

// ---- compile-time feature decode: TIGHT triangular packing ----------------
constexpr int PfxT(int d) { return 32 * d - (d * (d - 1)) / 2; }
constexpr int rowT(int p) { int d = 0; while (d < 31 && PfxT(d + 1) <= p) ++d; return d; }
constexpr int colT(int p) { return rowT(p) + (p - PfxT(rowT(p))); }

template<int P, int J>
__device__ __forceinline__ float genOne(const float (&x)[DIM]) {
    constexpr int p = P + J;
    if constexpr (p >= NREAL) {
        return 0.f;
    } else if constexpr (p >= 528) {
        return x[p - 528];
    } else {
        constexpr int d = rowT(p);
        constexpr int f = colT(p);
        static_assert(d >= 0 && d < 32 && f >= d && f < 32, "bad feature map");
        return x[d] * x[f];
    }
}

// ---------------------------------------------------------------------------
// Precompute: Psi column k scattered into frag-ordered PsiF (bf16), kc2 fp32.
// ---------------------------------------------------------------------------
__global__ __launch_bounds__(256) void gmm_pre(
    const float* __restrict__ S,
    const float* __restrict__ centers,
    const float* __restrict__ weights,
    unsigned short* __restrict__ PsiF,
    float* __restrict__ kc2)
{
    __shared__ float Sl[DIM][DIM + 1];
    __shared__ float As[DIM][DIM + 1];
    __shared__ float cl[DIM], ml[DIM];
    __shared__ float red[256];

    const int k = blockIdx.x, tid = threadIdx.x;

    for (int idx = tid; idx < DIM * DIM; idx += 256)
        Sl[idx >> 5][idx & 31] = S[(size_t)k * DIM * DIM + idx];
    if (tid < DIM) cl[tid] = centers[k * DIM + tid];
    __syncthreads();

    // A = S S^T
    for (int idx = tid; idx < DIM * DIM; idx += 256) {
        const int d = idx >> 5, f = idx & 31;
        float a = 0.f;
#pragma unroll
        for (int e = 0; e < DIM; ++e) a = fmaf(Sl[d][e], Sl[f][e], a);
        As[d][f] = a;
    }
    __syncthreads();

    if (tid < DIM) {
        float mv = 0.f;
#pragma unroll
        for (int f = 0; f < DIM; ++f) mv = fmaf(As[tid][f], cl[f], mv);
        ml[tid] = mv;
    }
    __syncthreads();

    // scatter Psi column k into frag positions (reads As diag+upper, ml).
    for (int p = tid; p < NREAL; p += 256) {
        float val;
        if (p < 528) {
            int d = 0, pr = 0;
            while (pr + (32 - d) <= p) { pr += (32 - d); ++d; }
            const int f = d + (p - pr);
            val = (f == d) ? -0.5f * As[d][d] : -As[d][f];
        } else {
            val = ml[p - 528];
        }
        const int c = p >> 6, kk = p & 63;
        const int s = kk >> 4, qq = (kk >> 3) & 1, j = kk & 7;
        const int ct = k >> 5, ll = qq * 32 + (k & 31);
        const int g = c * 2048 + (s * 8 + ct) * 64 + ll;
        PsiF[(size_t)g * 8 + j] = f2bf(val);
    }

    red[tid] = fabsf(weights[tid]);          // K == 256 == blockDim
    __syncthreads();                          // also fences As/ml reads above
    for (int off = 128; off > 0; off >>= 1) {
        if (tid < off) red[tid] += red[tid + off];
        __syncthreads();
    }
    const float wsum = red[0];

    // SPD Gaussian elimination: 1 barrier/step, logdet(A) = sum log(pivot_j).
    for (int j = 0; j < DIM - 1; ++j) {
        const float inv = 1.0f / As[j][j];
        for (int idx = tid; idx < DIM * DIM; idx += 256) {
            const int r = idx >> 5, c = idx & 31;
            if (r > j && c > j)
                As[r][c] = fmaf(-As[r][j] * inv, As[j][c], As[r][c]);
        }
        __syncthreads();
    }

    if (tid < DIM) red[tid] = __logf(As[tid][tid]);   // pivots > 0 (SPD)
    __syncthreads();
    if (tid == 0) {
        float sl = 0.f;
        for (int j = 0; j < DIM; ++j) sl += red[j];
        float cac = 0.f;
        for (int d2 = 0; d2 < DIM; ++d2) cac = fmaf(ml[d2], cl[d2], cac);
        kc2[k] = __logf(fabsf(weights[k])) - __logf(wsum + 1e-30f)
               + 0.5f * sl - 0.5f * cac;
    }
}

// ---------------------------------------------------------------------------
// Main MFMA kernel v14 = v13 (hybrid paths, A-reg prefetch, lane-local LSE)
// with 2-CHUNK BARRIER PERIODS: gen stages TWO chunks (64 feats, 8 KB) per
// period into a double-buffered 16 KB sA; ONE lgkm barrier per period -->
// 9 barriers/block instead of 17 (the barrier convoy is the last
// unexplained ~45 K cy/CU). A-frags for both chunks of the next period are
// prefetched into two register stages right after the barrier. B path
// (global->reg ping-pong, barrier-free) and epilogue identical to v13.
// ~96 VGPR + 64 AGPR = 160 <= 170 cap -> still 3 waves/SIMD.
// ---------------------------------------------------------------------------
template<int P>
__device__ __forceinline__ void genQuad(const float (&x)[DIM], float* v) {
    v[0] = genOne<P, 0>(x);
    v[1] = genOne<P, 1>(x);
    v[2] = genOne<P, 2>(x);
    v[3] = genOne<P, 3>(x);
}

// site SS (8 feats = k16-step SS>>1, k-group SS&1) of chunk CH, row l.
// sA stage = (CH>>1)&1 (8 KB per stage), chunk-within-period = CH&1.
template<int CH, int SS>
__device__ __forceinline__ void genSiteW(const float (&x)[DIM], uint4* sA4, int l) {
    float v[8];
    genQuad<CH * 32 + SS * 8>(x, v);
    genQuad<CH * 32 + SS * 8 + 4>(x, v + 4);
    uint4 u;
    u.x = pkbf(v[0], v[1]);
    u.y = pkbf(v[2], v[3]);
    u.z = pkbf(v[4], v[5]);
    u.w = pkbf(v[6], v[7]);
    uint4* base = sA4 + ((CH >> 1) & 1) * 512 + (CH & 1) * 256;
    base[(((SS >> 1) * 2 + (l >> 5)) << 6) + (SS & 1) * 32 + (l & 31)] = u;
}

// wave w gens site w of chunk CH for all 64 rows (lane l = row l).
template<int CH>
__device__ __forceinline__ void genChunkW(const float (&x)[DIM], uint4* sA4,
                                          int w, int l) {
    if constexpr (CH < 17) {
        if      (w == 0) genSiteW<CH, 0>(x, sA4, l);
        else if (w == 1) genSiteW<CH, 1>(x, sA4, l);
        else if (w == 2) genSiteW<CH, 2>(x, sA4, l);
        else             genSiteW<CH, 3>(x, sA4, l);
    } else {                             // chunk 17: 16 feats = sites 0,1
        if      (w == 0) genSiteW<CH, 0>(x, sA4, l);
        else if (w == 1) genSiteW<CH, 1>(x, sA4, l);
    }
}

// A-frag register read for chunk C (issued right after the period barrier).
template<int C>
__device__ __forceinline__ void readA(const uint4* sA4, uint4 (&ar)[4], int l) {
    const uint4* aa = sA4 + ((C >> 1) & 1) * 512 + (C & 1) * 256;
    ar[0] = aa[0 * 64 + l];
    ar[1] = aa[1 * 64 + l];
    if constexpr (C < 17) {
        ar[2] = aa[2 * 64 + l];
        ar[3] = aa[3 * 64 + l];
    }
}

// B (psi) granules for chunk C, wave cgp, lane l.
template<int C>
__device__ __forceinline__ void loadB(const uint4* __restrict__ PsiF4,
                                      uint4 (&st)[4], int l, int cgp) {
    const uint4* p = PsiF4 + C * 1024 + (cgp * 2) * 64 + l;
    st[0] = p[0];
    st[1] = p[64];
    if constexpr (C < 17) {
        st[2] = p[512];
        st[3] = p[512 + 64];
    }
}

// MFMA for one chunk from register operands.
template<int C>
__device__ __forceinline__ void mfmaChunk(const uint4 (&aR)[4], const uint4 (&bR)[4],
                                          f32x16 (&acc)[2][2]) {
    constexpr int NS = (C < 17) ? 2 : 1;
#pragma unroll
    for (int s2 = 0; s2 < NS; ++s2) {
        short8 f0 = __builtin_bit_cast(short8, aR[s2 * 2 + 0]);
        short8 f1 = __builtin_bit_cast(short8, aR[s2 * 2 + 1]);
#pragma unroll
        for (int cj = 0; cj < 2; ++cj) {
            short8 psi = __builtin_bit_cast(short8, bR[s2 * 2 + cj]);
            acc[0][cj] = __builtin_amdgcn_mfma_f32_32x32x16_bf16(psi, f0, acc[0][cj], 0, 0, 0);
            acc[1][cj] = __builtin_amdgcn_mfma_f32_32x32x16_bf16(psi, f1, acc[1][cj], 0, 0, 0);
        }
    }
}

// Period P covers chunks 2P, 2P+1. One barrier per period.
template<int P>
__device__ __forceinline__ void doPeriod(const float (&x)[DIM],
    uint4* sA4, const uint4* __restrict__ PsiF4,
    uint4 (&aA)[4], uint4 (&aB)[4], uint4 (&bA)[4], uint4 (&bB)[4],
    f32x16 (&acc)[2][2], int l, int w)
{
    constexpr int c0 = 2 * P, c1 = 2 * P + 1;
    // entry: aA/aB = A-frags(c0/c1) (reads issued after prev barrier);
    // bA = B(c0) (loaded last period); sA stage (P+1)&1 free.

    // -- chunk c0 --
    loadB<c1>(PsiF4, bB, l, w);                      // B(c1) in flight
    if constexpr (c0 + 2 < NCH) genChunkW<c0 + 2>(x, sA4, w, l);
    mfmaChunk<c0>(aA, bA, acc);

    // -- chunk c1 --
    if constexpr (c1 + 1 < NCH) loadB<c1 + 1>(PsiF4, bA, l, w);  // next period's B
    if constexpr (c0 + 3 < NCH) genChunkW<c0 + 3>(x, sA4, w, l);
    mfmaChunk<c1>(aB, bB, acc);

    // period barrier: publish gen(2P+2, 2P+3); then prefetch their A-frags.
    if constexpr (c1 + 1 < NCH) {
        barrier_lds();
        readA<c0 + 2>(sA4, aA, l);
        readA<c0 + 3>(sA4, aB, l);
    }
}

__global__ __launch_bounds__(256, 3) void gmm_mfma(
    const float* __restrict__ points,
    const unsigned short* __restrict__ PsiF,
    const float* __restrict__ kc2,
    const float* __restrict__ thr,
    float* __restrict__ out)
{
    __shared__ uint4 sA4[1024];          // 16 KB: feat 2-chunk dbuf (2 x 8 KB)
    __shared__ float sM[64][4];          // 1 KB epilogue scratch
    __shared__ float sS[64][4];          // 1 KB

    const int t = threadIdx.x;
    const int w = t >> 6, l = t & 63;    // w = gen site AND center-granule pair

    const uint4* PsiF4 = (const uint4*)PsiF;

    // x of row l (4 thr/row cache-served)
    float x[DIM];
    const float4* px = (const float4*)(points + ((size_t)blockIdx.x * 64 + l) * DIM);
#pragma unroll
    for (int j2 = 0; j2 < 8; ++j2) {
        float4 v = px[j2];
        x[4 * j2 + 0] = v.x; x[4 * j2 + 1] = v.y;
        x[4 * j2 + 2] = v.z; x[4 * j2 + 3] = v.w;
    }

    f32x16 acc[2][2];
#pragma unroll
    for (int ri = 0; ri < 2; ++ri)
#pragma unroll
        for (int cj = 0; cj < 2; ++cj)
#pragma unroll
            for (int r = 0; r < 16; ++r) acc[ri][cj][r] = 0.f;

    uint4 aA[4], aB[4], bA[4], bB[4];
    loadB<0>(PsiF4, bA, l, w);           // B(0) -> regs

    genChunkW<0>(x, sA4, w, l);          // period-0 feats (chunks 0,1)
    genChunkW<1>(x, sA4, w, l);
    barrier_lds();
    readA<0>(sA4, aA, l);
    readA<1>(sA4, aB, l);

    doPeriod<0>(x, sA4, PsiF4, aA, aB, bA, bB, acc, l, w);
    doPeriod<1>(x, sA4, PsiF4, aA, aB, bA, bB, acc, l, w);
    doPeriod<2>(x, sA4, PsiF4, aA, aB, bA, bB, acc, l, w);
    doPeriod<3>(x, sA4, PsiF4, aA, aB, bA, bB, acc, l, w);
    doPeriod<4>(x, sA4, PsiF4, aA, aB, bA, bB, acc, l, w);
    doPeriod<5>(x, sA4, PsiF4, aA, aB, bA, bB, acc, l, w);
    doPeriod<6>(x, sA4, PsiF4, aA, aB, bA, bB, acc, l, w);
    doPeriod<7>(x, sA4, PsiF4, aA, aB, bA, bB, acc, l, w);
    doPeriod<8>(x, sA4, PsiF4, aA, aB, bA, bB, acc, l, w);

    // ---- epilogue: lane-local LSE over this wave's 64 centers x 64 rows --
    // lane value (ri, cj, rg): row = ri*32 + (l&31),
    // center = (w*2 + cj)*32 + (rg&3) + 8*(rg>>2) + 4*(l>>5)
    const int hi = l >> 5;
    float mr[2] = { -INFINITY, -INFINITY };
#pragma unroll
    for (int cj = 0; cj < 2; ++cj) {
        const float* kp = kc2 + (w * 2 + cj) * 32 + 4 * hi;
        const float4 q0 = *(const float4*)(kp);
        const float4 q1 = *(const float4*)(kp + 8);
        const float4 q2 = *(const float4*)(kp + 16);
        const float4 q3 = *(const float4*)(kp + 24);
#pragma unroll
        for (int ri = 0; ri < 2; ++ri) {
#define KADD(R, QC) { float _v = acc[ri][cj][R] + (QC); acc[ri][cj][R] = _v; mr[ri] = fmaxf(mr[ri], _v); }
            KADD(0, q0.x)  KADD(1, q0.y)  KADD(2, q0.z)  KADD(3, q0.w)
            KADD(4, q1.x)  KADD(5, q1.y)  KADD(6, q1.z)  KADD(7, q1.w)
            KADD(8, q2.x)  KADD(9, q2.y)  KADD(10, q2.z) KADD(11, q2.w)
            KADD(12, q3.x) KADD(13, q3.y) KADD(14, q3.z) KADD(15, q3.w)
#undef KADD
        }
    }
#pragma unroll
    for (int ri = 0; ri < 2; ++ri) {
        float m = fmaxf(mr[ri], __shfl_xor(mr[ri], 32, 64));
        float sv = 0.f;
#pragma unroll
        for (int cj = 0; cj < 2; ++cj)
#pragma unroll
            for (int rg = 0; rg < 16; ++rg)
                sv += __expf(acc[ri][cj][rg] - m);
        sv += __shfl_xor(sv, 32, 64);
        if (l < 32) {
            sM[ri * 32 + l][w] = m;
            sS[ri * 32 + l][w] = sv;
        }
    }
    __syncthreads();

    if (t < 64) {
        const float m0 = sM[t][0], m1 = sM[t][1], m2 = sM[t][2], m3 = sM[t][3];
        const float M = fmaxf(fmaxf(m0, m1), fmaxf(m2, m3));
        const float Sv = sS[t][0] * __expf(m0 - M) + sS[t][1] * __expf(m1 - M)
                       + sS[t][2] * __expf(m2 - M) + sS[t][3] * __expf(m3 - M);
        out[(size_t)blockIdx.x * 64 + t] = M + __logf(Sv) - thr[0];
    }
}

extern "C" void kernel_launch(void* const* d_in, const int* in_sizes, int n_in,
                              void* d_out, int out_size, void* d_ws, size_t ws_size,
                              hipStream_t stream) {
    const float* points  = (const float*)d_in[0];
    const float* centers = (const float*)d_in[1];
    const float* covs    = (const float*)d_in[2];
    const float* weights = (const float*)d_in[3];
    const float* thr     = (const float*)d_in[4];
    float* out = (float*)d_out;

    unsigned short* PsiF = (unsigned short*)d_ws;
    float* kc2 = (float*)((char*)d_ws + PSIF_BYTES);

    gmm_pre<<<KCOMP, 256, 0, stream>>>(covs, centers, weights, PsiF, kc2);
    gmm_mfma<<<NPTS / 64, 256, 0, stream>>>(points, PsiF, kc2, thr, out);
}

// Round 15
// 129.308 us; speedup vs baseline: 1.0456x; 1.0456x over previous
//
#include <hip/hip_runtime.h>
#include <math.h>

#define NPTS 131072
#define KCOMP 256
#define DIM 32
#define NREAL 560                 // 528 tight-packed quad + 32 linear
#define NCH 18                    // 32-feature chunks: 17 full + 1 half (16)
#define PSIF_BYTES 294912         // 18 chunks * 1024 granules * 16 B
#define WS_NEED (PSIF_BYTES + KCOMP * 4)

typedef __attribute__((ext_vector_type(8))) short short8;
typedef __attribute__((ext_vector_type(16))) float f32x16;

__device__ __forceinline__ unsigned short f2bf(float v) {
    unsigned u = __float_as_uint(v);
    u += 0x7fffu + ((u >> 16) & 1u);   // RNE
    return (unsigned short)(u >> 16);
}

// pack two f32 -> two bf16 (lo | hi<<16). RTN (+0x8000) + byte-perm: 3 ops.
__device__ __forceinline__ unsigned pkbf(float lo, float hi) {
#if __has_builtin(__builtin_amdgcn_perm)
    const unsigned a = __float_as_uint(hi) + 0x8000u;
    const unsigned b = __float_as_uint(lo) + 0x8000u;
    return __builtin_amdgcn_perm(a, b, 0x07060302u);
#else
    return (unsigned)f2bf(lo) | ((unsigned)f2bf(hi) << 16);
#endif
}

// LDS-only barrier: gen writes are the only shared-memory traffic in the
// main loop; B loads are wave-private register deps and are NOT drained.
__device__ __forceinline__ void barrier_lds() {
    asm volatile("s_waitcnt lgkmcnt(0)\ns_barrier" ::: "memory");
}

// ---- compile-time feature decode: TIGHT triangular packing ----------------
constexpr int PfxT(int d) { return 32 * d - (d * (d - 1)) / 2; }
constexpr int rowT(int p) { int d = 0; while (d < 31 && PfxT(d + 1) <= p) ++d; return d; }
constexpr int colT(int p) { return rowT(p) + (p - PfxT(rowT(p))); }

template<int P, int J>
__device__ __forceinline__ float genOne(const float (&x)[DIM]) {
    constexpr int p = P + J;
    if constexpr (p >= NREAL) {
        return 0.f;
    } else if constexpr (p >= 528) {
        return x[p - 528];
    } else {
        constexpr int d = rowT(p);
        constexpr int f = colT(p);
        static_assert(d >= 0 && d < 32 && f >= d && f < 32, "bad feature map");
        return x[d] * x[f];
    }
}

// ---------------------------------------------------------------------------
// Precompute: Psi column k scattered into frag-ordered PsiF (bf16), kc2 fp32.
// ---------------------------------------------------------------------------
__global__ __launch_bounds__(256) void gmm_pre(
    const float* __restrict__ S,
    const float* __restrict__ centers,
    const float* __restrict__ weights,
    unsigned short* __restrict__ PsiF,
    float* __restrict__ kc2)
{
    __shared__ float Sl[DIM][DIM + 1];
    __shared__ float As[DIM][DIM + 1];
    __shared__ float cl[DIM], ml[DIM];
    __shared__ float red[256];

    const int k = blockIdx.x, tid = threadIdx.x;

    for (int idx = tid; idx < DIM * DIM; idx += 256)
        Sl[idx >> 5][idx & 31] = S[(size_t)k * DIM * DIM + idx];
    if (tid < DIM) cl[tid] = centers[k * DIM + tid];
    __syncthreads();

    // A = S S^T
    for (int idx = tid; idx < DIM * DIM; idx += 256) {
        const int d = idx >> 5, f = idx & 31;
        float a = 0.f;
#pragma unroll
        for (int e = 0; e < DIM; ++e) a = fmaf(Sl[d][e], Sl[f][e], a);
        As[d][f] = a;
    }
    __syncthreads();

    if (tid < DIM) {
        float mv = 0.f;
#pragma unroll
        for (int f = 0; f < DIM; ++f) mv = fmaf(As[tid][f], cl[f], mv);
        ml[tid] = mv;
    }
    __syncthreads();

    // scatter Psi column k into frag positions (reads As diag+upper, ml).
    for (int p = tid; p < NREAL; p += 256) {
        float val;
        if (p < 528) {
            int d = 0, pr = 0;
            while (pr + (32 - d) <= p) { pr += (32 - d); ++d; }
            const int f = d + (p - pr);
            val = (f == d) ? -0.5f * As[d][d] : -As[d][f];
        } else {
            val = ml[p - 528];
        }
        const int c = p >> 6, kk = p & 63;
        const int s = kk >> 4, qq = (kk >> 3) & 1, j = kk & 7;
        const int ct = k >> 5, ll = qq * 32 + (k & 31);
        const int g = c * 2048 + (s * 8 + ct) * 64 + ll;
        PsiF[(size_t)g * 8 + j] = f2bf(val);
    }

    red[tid] = fabsf(weights[tid]);          // K == 256 == blockDim
    __syncthreads();                          // also fences As/ml reads above
    for (int off = 128; off > 0; off >>= 1) {
        if (tid < off) red[tid] += red[tid + off];
        __syncthreads();
    }
    const float wsum = red[0];

    // SPD Gaussian elimination: 1 barrier/step, logdet(A) = sum log(pivot_j).
    for (int j = 0; j < DIM - 1; ++j) {
        const float inv = 1.0f / As[j][j];
        for (int idx = tid; idx < DIM * DIM; idx += 256) {
            const int r = idx >> 5, c = idx & 31;
            if (r > j && c > j)
                As[r][c] = fmaf(-As[r][j] * inv, As[j][c], As[r][c]);
        }
        __syncthreads();
    }

    if (tid < DIM) red[tid] = __logf(As[tid][tid]);   // pivots > 0 (SPD)
    __syncthreads();
    if (tid == 0) {
        float sl = 0.f;
        for (int j = 0; j < DIM; ++j) sl += red[j];
        float cac = 0.f;
        for (int d2 = 0; d2 < DIM; ++d2) cac = fmaf(ml[d2], cl[d2], cac);
        kc2[k] = __logf(fabsf(weights[k])) - __logf(wsum + 1e-30f)
               + 0.5f * sl - 0.5f * cac;
    }
}

// ---------------------------------------------------------------------------
// Main MFMA kernel v15 = v13's register budget (ONE aReg stage + bA/bB =
// 48 staging VGPRs -- v14's 4th stage spilled: WRITE 0.5->5.5 MB) with
// 2-CHUNK BARRIER PERIODS: one lgkm barrier per 2 chunks (9 vs 17).
// Chunk c1's A-frags re-read into the SAME aReg stage mid-period (WAR after
// c0's MFMAs), covered by loadB-issue + gen(c0+3) VALU. Gen writes go to
// the opposite 8 KB sA stage, published by the period-end barrier.
// This isolates barrier count as the LAST untested scheduling variable.
// ---------------------------------------------------------------------------
template<int P>
__device__ __forceinline__ void genQuad(const float (&x)[DIM], float* v) {
    v[0] = genOne<P, 0>(x);
    v[1] = genOne<P, 1>(x);
    v[2] = genOne<P, 2>(x);
    v[3] = genOne<P, 3>(x);
}

// site SS (8 feats = k16-step SS>>1, k-group SS&1) of chunk CH, row l.
// sA stage = (CH>>1)&1 (8 KB), chunk-within-period sub-buffer = CH&1 (4 KB).
template<int CH, int SS>
__device__ __forceinline__ void genSiteW(const float (&x)[DIM], uint4* sA4, int l) {
    float v[8];
    genQuad<CH * 32 + SS * 8>(x, v);
    genQuad<CH * 32 + SS * 8 + 4>(x, v + 4);
    uint4 u;
    u.x = pkbf(v[0], v[1]);
    u.y = pkbf(v[2], v[3]);
    u.z = pkbf(v[4], v[5]);
    u.w = pkbf(v[6], v[7]);
    uint4* base = sA4 + ((CH >> 1) & 1) * 512 + (CH & 1) * 256;
    base[(((SS >> 1) * 2 + (l >> 5)) << 6) + (SS & 1) * 32 + (l & 31)] = u;
}

// wave w gens site w of chunk CH for all 64 rows (lane l = row l).
template<int CH>
__device__ __forceinline__ void genChunkW(const float (&x)[DIM], uint4* sA4,
                                          int w, int l) {
    if constexpr (CH < 17) {
        if      (w == 0) genSiteW<CH, 0>(x, sA4, l);
        else if (w == 1) genSiteW<CH, 1>(x, sA4, l);
        else if (w == 2) genSiteW<CH, 2>(x, sA4, l);
        else             genSiteW<CH, 3>(x, sA4, l);
    } else {                             // chunk 17: 16 feats = sites 0,1
        if      (w == 0) genSiteW<CH, 0>(x, sA4, l);
        else if (w == 1) genSiteW<CH, 1>(x, sA4, l);
    }
}

// A-frag register read for chunk C into the single aReg stage.
template<int C>
__device__ __forceinline__ void readA(const uint4* sA4, uint4 (&ar)[4], int l) {
    const uint4* aa = sA4 + ((C >> 1) & 1) * 512 + (C & 1) * 256;
    ar[0] = aa[0 * 64 + l];
    ar[1] = aa[1 * 64 + l];
    if constexpr (C < 17) {
        ar[2] = aa[2 * 64 + l];
        ar[3] = aa[3 * 64 + l];
    }
}

// B (psi) granules for chunk C, wave cgp, lane l.
template<int C>
__device__ __forceinline__ void loadB(const uint4* __restrict__ PsiF4,
                                      uint4 (&st)[4], int l, int cgp) {
    const uint4* p = PsiF4 + C * 1024 + (cgp * 2) * 64 + l;
    st[0] = p[0];
    st[1] = p[64];
    if constexpr (C < 17) {
        st[2] = p[512];
        st[3] = p[512 + 64];
    }
}

// MFMA for one chunk from register operands.
template<int C>
__device__ __forceinline__ void mfmaChunk(const uint4 (&aR)[4], const uint4 (&bR)[4],
                                          f32x16 (&acc)[2][2]) {
    constexpr int NS = (C < 17) ? 2 : 1;
#pragma unroll
    for (int s2 = 0; s2 < NS; ++s2) {
        short8 f0 = __builtin_bit_cast(short8, aR[s2 * 2 + 0]);
        short8 f1 = __builtin_bit_cast(short8, aR[s2 * 2 + 1]);
#pragma unroll
        for (int cj = 0; cj < 2; ++cj) {
            short8 psi = __builtin_bit_cast(short8, bR[s2 * 2 + cj]);
            acc[0][cj] = __builtin_amdgcn_mfma_f32_32x32x16_bf16(psi, f0, acc[0][cj], 0, 0, 0);
            acc[1][cj] = __builtin_amdgcn_mfma_f32_32x32x16_bf16(psi, f1, acc[1][cj], 0, 0, 0);
        }
    }
}

// Period P covers chunks 2P, 2P+1. ONE barrier per period.
template<int P>
__device__ __forceinline__ void doPeriod(const float (&x)[DIM],
    uint4* sA4, const uint4* __restrict__ PsiF4,
    uint4 (&aReg)[4], uint4 (&bA)[4], uint4 (&bB)[4],
    f32x16 (&acc)[2][2], int l, int w)
{
    constexpr int c0 = 2 * P, c1 = 2 * P + 1;
    // entry: aReg = A(c0) (read after prev barrier); bA = B(c0) (loaded
    // last period); sA stage (P+1)&1 free (sealed by prev barrier).

    // -- chunk c0 --
    loadB<c1>(PsiF4, bB, l, w);                      // B(c1) in flight
    if constexpr (c0 + 2 < NCH) genChunkW<c0 + 2>(x, sA4, w, l);
    mfmaChunk<c0>(aReg, bA, acc);

    // re-read aReg with c1's A-frags (WAR: c0's MFMAs consumed it above);
    // latency covered by loadB(c0+2)-issue + gen(c0+3) below.
    readA<c1>(sA4, aReg, l);
    if constexpr (c0 + 2 < NCH) loadB<c0 + 2>(PsiF4, bA, l, w);  // next period's B
    if constexpr (c0 + 3 < NCH) genChunkW<c0 + 3>(x, sA4, w, l);

    // -- chunk c1 --
    mfmaChunk<c1>(aReg, bB, acc);

    // period barrier: publish gen(2P+2, 2P+3); then prefetch A(2P+2).
    if constexpr (c1 + 1 < NCH) {
        barrier_lds();
        readA<c0 + 2>(sA4, aReg, l);
    }
}

__global__ __launch_bounds__(256, 3) void gmm_mfma(
    const float* __restrict__ points,
    const unsigned short* __restrict__ PsiF,
    const float* __restrict__ kc2,
    const float* __restrict__ thr,
    float* __restrict__ out)
{
    __shared__ uint4 sA4[1024];          // 16 KB: feat 2-chunk dbuf (2 x 8 KB)
    __shared__ float sM[64][4];          // 1 KB epilogue scratch
    __shared__ float sS[64][4];          // 1 KB

    const int t = threadIdx.x;
    const int w = t >> 6, l = t & 63;    // w = gen site AND center-granule pair

    const uint4* PsiF4 = (const uint4*)PsiF;

    // x of row l (4 thr/row cache-served)
    float x[DIM];
    const float4* px = (const float4*)(points + ((size_t)blockIdx.x * 64 + l) * DIM);
#pragma unroll
    for (int j2 = 0; j2 < 8; ++j2) {
        float4 v = px[j2];
        x[4 * j2 + 0] = v.x; x[4 * j2 + 1] = v.y;
        x[4 * j2 + 2] = v.z; x[4 * j2 + 3] = v.w;
    }

    f32x16 acc[2][2];
#pragma unroll
    for (int ri = 0; ri < 2; ++ri)
#pragma unroll
        for (int cj = 0; cj < 2; ++cj)
#pragma unroll
            for (int r = 0; r < 16; ++r) acc[ri][cj][r] = 0.f;

    uint4 aReg[4], bA[4], bB[4];
    loadB<0>(PsiF4, bA, l, w);           // B(0) -> regs

    genChunkW<0>(x, sA4, w, l);          // period-0 feats (chunks 0,1)
    genChunkW<1>(x, sA4, w, l);
    barrier_lds();
    readA<0>(sA4, aReg, l);

    doPeriod<0>(x, sA4, PsiF4, aReg, bA, bB, acc, l, w);
    doPeriod<1>(x, sA4, PsiF4, aReg, bA, bB, acc, l, w);
    doPeriod<2>(x, sA4, PsiF4, aReg, bA, bB, acc, l, w);
    doPeriod<3>(x, sA4, PsiF4, aReg, bA, bB, acc, l, w);
    doPeriod<4>(x, sA4, PsiF4, aReg, bA, bB, acc, l, w);
    doPeriod<5>(x, sA4, PsiF4, aReg, bA, bB, acc, l, w);
    doPeriod<6>(x, sA4, PsiF4, aReg, bA, bB, acc, l, w);
    doPeriod<7>(x, sA4, PsiF4, aReg, bA, bB, acc, l, w);
    doPeriod<8>(x, sA4, PsiF4, aReg, bA, bB, acc, l, w);

    // ---- epilogue: lane-local LSE over this wave's 64 centers x 64 rows --
    // lane value (ri, cj, rg): row = ri*32 + (l&31),
    // center = (w*2 + cj)*32 + (rg&3) + 8*(rg>>2) + 4*(l>>5)
    const int hi = l >> 5;
    float mr[2] = { -INFINITY, -INFINITY };
#pragma unroll
    for (int cj = 0; cj < 2; ++cj) {
        const float* kp = kc2 + (w * 2 + cj) * 32 + 4 * hi;
        const float4 q0 = *(const float4*)(kp);
        const float4 q1 = *(const float4*)(kp + 8);
        const float4 q2 = *(const float4*)(kp + 16);
        const float4 q3 = *(const float4*)(kp + 24);
#pragma unroll
        for (int ri = 0; ri < 2; ++ri) {
#define KADD(R, QC) { float _v = acc[ri][cj][R] + (QC); acc[ri][cj][R] = _v; mr[ri] = fmaxf(mr[ri], _v); }
            KADD(0, q0.x)  KADD(1, q0.y)  KADD(2, q0.z)  KADD(3, q0.w)
            KADD(4, q1.x)  KADD(5, q1.y)  KADD(6, q1.z)  KADD(7, q1.w)
            KADD(8, q2.x)  KADD(9, q2.y)  KADD(10, q2.z) KADD(11, q2.w)
            KADD(12, q3.x) KADD(13, q3.y) KADD(14, q3.z) KADD(15, q3.w)
#undef KADD
        }
    }
#pragma unroll
    for (int ri = 0; ri < 2; ++ri) {
        float m = fmaxf(mr[ri], __shfl_xor(mr[ri], 32, 64));
        float sv = 0.f;
#pragma unroll
        for (int cj = 0; cj < 2; ++cj)
#pragma unroll
            for (int rg = 0; rg < 16; ++rg)
                sv += __expf(acc[ri][cj][rg] - m);
        sv += __shfl_xor(sv, 32, 64);
        if (l < 32) {
            sM[ri * 32 + l][w] = m;
            sS[ri * 32 + l][w] = sv;
        }
    }
    __syncthreads();

    if (t < 64) {
        const float m0 = sM[t][0], m1 = sM[t][1], m2 = sM[t][2], m3 = sM[t][3];
        const float M = fmaxf(fmaxf(m0, m1), fmaxf(m2, m3));
        const float Sv = sS[t][0] * __expf(m0 - M) + sS[t][1] * __expf(m1 - M)
                       + sS[t][2] * __expf(m2 - M) + sS[t][3] * __expf(m3 - M);
        out[(size_t)blockIdx.x * 64 + t] = M + __logf(Sv) - thr[0];
    }
}

extern "C" void kernel_launch(void* const* d_in, const int* in_sizes, int n_in,
                              void* d_out, int out_size, void* d_ws, size_t ws_size,
                              hipStream_t stream) {
    const float* points  = (const float*)d_in[0];
    const float* centers = (const float*)d_in[1];
    const float* covs    = (const float*)d_in[2];
    const float* weights = (const float*)d_in[3];
    const float* thr     = (const float*)d_in[4];
    float* out = (float*)d_out;

    unsigned short* PsiF = (unsigned short*)d_ws;
    float* kc2 = (float*)((char*)d_ws + PSIF_BYTES);

    gmm_pre<<<KCOMP, 256, 0, stream>>>(covs, centers, weights, PsiF, kc2);
    gmm_mfma<<<NPTS / 64, 256, 0, stream>>>(points, PsiF, kc2, thr, out);
}